// Round 2
// 454.015 us; speedup vs baseline: 1.0388x; 1.0388x over previous
//
#include <hip/hip_runtime.h>
#include <hip/hip_bf16.h>

typedef __attribute__((ext_vector_type(8))) short short8;
typedef __attribute__((ext_vector_type(4))) float floatx4;

// ---------- helpers ----------
__device__ __forceinline__ unsigned short f32_to_bf16(float f) {
    unsigned int u = __builtin_bit_cast(unsigned int, f);
    u = (u + 0x7FFFu + ((u >> 16) & 1u)) >> 16;   // RNE
    return (unsigned short)u;
}
__device__ __forceinline__ unsigned int pack_bf16x2(float lo, float hi) {
    return (unsigned int)f32_to_bf16(lo) | ((unsigned int)f32_to_bf16(hi) << 16);
}
// async global->LDS, 16B per lane; LDS dest = wave-uniform base + lane*16
__device__ __forceinline__ void async_load16(const unsigned short* g, unsigned short* l) {
    __builtin_amdgcn_global_load_lds(
        (const __attribute__((address_space(1))) void*)g,
        (__attribute__((address_space(3))) void*)l, 16, 0, 0);
}

// ---------- transpose tile: Wt[n][k] = W[k][n_off+n], 32x32 ----------
__device__ __forceinline__ void transpose_tile(
    const float* __restrict__ W, int src_ld, int n_off,
    unsigned short* __restrict__ Wt, int dst_ld, int nb, int kb, int tid) {
    __shared__ float tile[32][33];
    int n0 = nb * 32, k0 = kb * 32;
    int tx = tid & 31, ty = tid >> 5;    // ty 0..7
#pragma unroll
    for (int p = 0; p < 4; ++p) {
        int r = ty + 8 * p;
        tile[r][tx] = W[(long)(k0 + r) * src_ld + n_off + n0 + tx];
    }
    __syncthreads();
#pragma unroll
    for (int p = 0; p < 4; ++p) {
        int r = ty + 8 * p;
        Wt[(long)(n0 + r) * dst_ld + k0 + tx] = f32_to_bf16(tile[tx][r]);
    }
}

__device__ __forceinline__ void cast8(
    const float* __restrict__ src, unsigned short* __restrict__ dst) {
    floatx4 a = *(const floatx4*)src;
    floatx4 b = *(const floatx4*)(src + 4);
    uint4 p;
    p.x = pack_bf16x2(a[0], a[1]); p.y = pack_bf16x2(a[2], a[3]);
    p.z = pack_bf16x2(b[0], b[1]); p.w = pack_bf16x2(b[2], b[3]);
    *(uint4*)dst = p;
}

// nontemporal variant for streamed-once context reads (keep L2/L3 for qt/wctx)
__device__ __forceinline__ void cast8_nt(
    const float* __restrict__ src, unsigned short* __restrict__ dst) {
    floatx4 a = __builtin_nontemporal_load((const floatx4*)src);
    floatx4 b = __builtin_nontemporal_load((const floatx4*)(src + 4));
    uint4 p;
    p.x = pack_bf16x2(a[0], a[1]); p.y = pack_bf16x2(a[2], a[3]);
    p.z = pack_bf16x2(b[0], b[1]); p.w = pack_bf16x2(b[2], b[3]);
    *(uint4*)dst = p;
}

// ---------- fused prep ----------
// blocks: [0,1024) WqT | [1024,2048) WvT | [2048,3072) WoutT |
//         [3072,3584) WkB strided cast | [3584,4608) x cast
__global__ __launch_bounds__(256) void prep_kernel(
    const float* __restrict__ Wq, const float* __restrict__ Wkv,
    const float* __restrict__ Wout, const float* __restrict__ x,
    unsigned short* __restrict__ WqT, unsigned short* __restrict__ WkB,
    unsigned short* __restrict__ WvT, unsigned short* __restrict__ WoutT,
    unsigned short* __restrict__ xb) {
    int id = blockIdx.x, tid = threadIdx.x;
    if (id < 1024) { transpose_tile(Wq,   1024, 0,    WqT,   1024, id & 31, id >> 5, tid); return; }
    id -= 1024;
    if (id < 1024) { transpose_tile(Wkv,  2048, 1024, WvT,   1024, id & 31, id >> 5, tid); return; }
    id -= 1024;
    if (id < 1024) { transpose_tile(Wout, 1024, 0,    WoutT, 1024, id & 31, id >> 5, tid); return; }
    id -= 1024;
    if (id < 512) {   // WkB[c][d] = bf16(Wkv[c][d]), d<1024
        long e = ((long)id * 256 + tid) * 8;
        long row = e >> 10, col = e & 1023;
        cast8(Wkv + row * 2048 + col, WkB + e);
        return;
    }
    id -= 512;
    { long e = ((long)id * 256 + tid) * 8; cast8(x + e, xb + e); }
}

// ---------- GEMM 128x64 tile (used for qt: many small-K blocks) ----------
__global__ __launch_bounds__(256, 4) void gemm64_kernel(
    const unsigned short* __restrict__ A, long sA, int lda,
    const unsigned short* __restrict__ Bt, long sB, int ldb,
    void* __restrict__ C, long sC, int ldc,
    const float* __restrict__ bias, int K, int out_bf16) {
    __shared__ unsigned short As[128 * 32];   // 8 KB
    __shared__ unsigned short Bs[64 * 32];    // 4 KB

    const int tid = threadIdx.x, wave = tid >> 6, lane = tid & 63;
    const int z = blockIdx.z;
    A  += (long)z * sA;
    Bt += (long)z * sB;
    const int m0 = blockIdx.y * 128, n0 = blockIdx.x * 64;

    floatx4 acc[2][4];
#pragma unroll
    for (int i = 0; i < 2; ++i)
#pragma unroll
        for (int j = 0; j < 4; ++j) acc[i][j] = (floatx4)0.0f;

    const int kofs = (lane & 3) * 8;
    const unsigned short* aAddr = A  + (long)(m0 + wave * 32 + (lane >> 2)) * lda + kofs;
    const unsigned short* bAddr = Bt + (long)(n0 + wave * 16 + (lane >> 2)) * ldb + kofs;
    unsigned short* asBase = &As[wave * 1024];
    unsigned short* bsBase = &Bs[wave * 512];

    const int frm = lane & 15, fk = (lane >> 4) * 8;

    for (int kk = 0; kk < K; kk += 32) {
        __syncthreads();
        async_load16(aAddr + kk,                  asBase);
        async_load16(aAddr + (long)16 * lda + kk, asBase + 512);
        async_load16(bAddr + kk,                  bsBase);
        __syncthreads();

        short8 afrag[2], bfrag[4];
#pragma unroll
        for (int rt = 0; rt < 2; ++rt)
            afrag[rt] = *(const short8*)&As[(wave * 32 + rt * 16 + frm) * 32 + fk];
#pragma unroll
        for (int ct = 0; ct < 4; ++ct)
            bfrag[ct] = *(const short8*)&Bs[(ct * 16 + frm) * 32 + fk];
#pragma unroll
        for (int rt = 0; rt < 2; ++rt)
#pragma unroll
            for (int ct = 0; ct < 4; ++ct)
                acc[rt][ct] = __builtin_amdgcn_mfma_f32_16x16x32_bf16(
                    afrag[rt], bfrag[ct], acc[rt][ct], 0, 0, 0);
    }

    const int orow0 = m0 + wave * 32 + (lane >> 4) * 4;
    const int ocol0 = n0 + (lane & 15);
    if (out_bf16) {
        unsigned short* Cb = (unsigned short*)C + (long)z * sC;
#pragma unroll
        for (int rt = 0; rt < 2; ++rt)
#pragma unroll
            for (int r = 0; r < 4; ++r) {
                long row = orow0 + rt * 16 + r;
#pragma unroll
                for (int ct = 0; ct < 4; ++ct)
                    Cb[row * ldc + ocol0 + ct * 16] = f32_to_bf16(acc[rt][ct][r]);
            }
    } else {
        float* Cf = (float*)C + (long)z * sC;
#pragma unroll
        for (int rt = 0; rt < 2; ++rt)
#pragma unroll
            for (int r = 0; r < 4; ++r) {
                long row = orow0 + rt * 16 + r;
#pragma unroll
                for (int ct = 0; ct < 4; ++ct) {
                    int col = ocol0 + ct * 16;
                    float v = acc[rt][ct][r];
                    if (bias) v += bias[col];
                    Cf[row * ldc + col] = v;
                }
            }
    }
}

// ---------- GEMM 64x64 tile: doubles grid for 256-block-class launches ----------
__global__ __launch_bounds__(256, 4) void gemm64s_kernel(
    const unsigned short* __restrict__ A, long sA, int lda,
    const unsigned short* __restrict__ Bt, long sB, int ldb,
    void* __restrict__ C, long sC, int ldc,
    const float* __restrict__ bias, int K, int out_bf16) {
    __shared__ unsigned short As[64 * 32];   // 4 KB
    __shared__ unsigned short Bs[64 * 32];   // 4 KB

    const int tid = threadIdx.x, wave = tid >> 6, lane = tid & 63;
    const int z = blockIdx.z;
    A  += (long)z * sA;
    Bt += (long)z * sB;
    const int m0 = blockIdx.y * 64, n0 = blockIdx.x * 64;

    floatx4 acc[4];
#pragma unroll
    for (int j = 0; j < 4; ++j) acc[j] = (floatx4)0.0f;

    const int kofs = (lane & 3) * 8;
    const unsigned short* aAddr = A  + (long)(m0 + wave * 16 + (lane >> 2)) * lda + kofs;
    const unsigned short* bAddr = Bt + (long)(n0 + wave * 16 + (lane >> 2)) * ldb + kofs;
    unsigned short* asBase = &As[wave * 512];
    unsigned short* bsBase = &Bs[wave * 512];

    const int frm = lane & 15, fk = (lane >> 4) * 8;

    for (int kk = 0; kk < K; kk += 32) {
        __syncthreads();
        async_load16(aAddr + kk, asBase);
        async_load16(bAddr + kk, bsBase);
        __syncthreads();

        short8 afrag = *(const short8*)&As[(wave * 16 + frm) * 32 + fk];
        short8 bfrag[4];
#pragma unroll
        for (int ct = 0; ct < 4; ++ct)
            bfrag[ct] = *(const short8*)&Bs[(ct * 16 + frm) * 32 + fk];
#pragma unroll
        for (int ct = 0; ct < 4; ++ct)
            acc[ct] = __builtin_amdgcn_mfma_f32_16x16x32_bf16(
                afrag, bfrag[ct], acc[ct], 0, 0, 0);
    }

    const int orow0 = m0 + wave * 16 + (lane >> 4) * 4;
    const int ocol0 = n0 + (lane & 15);
    if (out_bf16) {
        unsigned short* Cb = (unsigned short*)C + (long)z * sC;
#pragma unroll
        for (int r = 0; r < 4; ++r) {
            long row = orow0 + r;
#pragma unroll
            for (int ct = 0; ct < 4; ++ct)
                Cb[row * ldc + ocol0 + ct * 16] = f32_to_bf16(acc[ct][r]);
        }
    } else {
        float* Cf = (float*)C + (long)z * sC;
#pragma unroll
        for (int r = 0; r < 4; ++r) {
            long row = orow0 + r;
#pragma unroll
            for (int ct = 0; ct < 4; ++ct) {
                int col = ocol0 + ct * 16;
                float v = acc[ct][r];
                if (bias) v += bias[col];
                Cf[row * ldc + col] = v;
            }
        }
    }
}

// ---------- fused attention: s = qt.ctx^T -> softmax -> wctx = p.ctx ----------
// one block per (b,i); 32 ctx rows j=i+128t loaded once (fp32->bf16 LDS).
// LDS rows XOR-swizzled on t-bits 3..4 (byte bits 5..6): PV column reads go
// from 8-way bank conflict to conflict-free; QK b128 row reads stay <=2-way.
#define CLD 1032   // LDS row stride (elems); rows 16B-aligned
__device__ __forceinline__ int swzb(int t, int c) {   // byte offset into ctx_t
    return t * (2 * CLD) + ((2 * c) ^ (((t >> 3) & 3) << 5));
}
__global__ __launch_bounds__(256, 2) void attn_fused_kernel(
    const float* __restrict__ ctx,          // fp32 [16*4096][1024]
    const unsigned short* __restrict__ qt,  // bf16 [2048][16][1024]
    unsigned short* __restrict__ wctx) {    // bf16 [2048][16][1024]
    __shared__ unsigned short ctx_t[32 * CLD];   // 66 KB (swizzled)
    __shared__ float sred[4 * 544];              // 8.5 KB, stride 17 per t-row
    __shared__ unsigned short p_l[16 * 40];      // p in frag layout [h][t], padded

    const int tid = threadIdx.x, wave = tid >> 6, lane = tid & 63;
    const int bi = blockIdx.x;
    const int b = bi >> 7, i = bi & 127;
    const int frm = lane & 15, fk = (lane >> 4) * 8;

    // preload qt A-frags into registers: lane holds head row frm,
    // k-range wave*256 + it*32 + fk .. +8
    short8 af[8];
    const unsigned short* qbase =
        qt + (long)bi * 16384 + (long)frm * 1024 + wave * 256 + fk;
#pragma unroll
    for (int it = 0; it < 8; ++it) af[it] = *(const short8*)(qbase + it * 32);

    // load ctx rows j=i+128t (fp32 -> bf16, nontemporal, swizzled LDS store)
#pragma unroll
    for (int rr = 0; rr < 16; ++rr) {
        int idx = rr * 2048 + tid * 8;
        int t = idx >> 10, c = idx & 1023;
        cast8_nt(ctx + ((long)b * 4096 + i + t * 128) * 1024 + c,
                 (unsigned short*)((char*)ctx_t + swzb(t, c)));
    }
    __syncthreads();

    // s partials: wave w covers k in [w*256, w*256+256)
    floatx4 acc0 = (floatx4)0.0f, acc1 = (floatx4)0.0f;
    __builtin_amdgcn_s_setprio(1);
#pragma unroll
    for (int it = 0; it < 8; ++it) {
        int kk = wave * 256 + it * 32;
        short8 b0 = *(const short8*)((const char*)ctx_t + swzb(frm, kk + fk));
        short8 b1 = *(const short8*)((const char*)ctx_t + swzb(16 + frm, kk + fk));
        acc0 = __builtin_amdgcn_mfma_f32_16x16x32_bf16(af[it], b0, acc0, 0, 0, 0);
        acc1 = __builtin_amdgcn_mfma_f32_16x16x32_bf16(af[it], b1, acc1, 0, 0, 0);
    }
    __builtin_amdgcn_s_setprio(0);
    // C-layout: t = lane&15 (+16 for acc1), h = (lane>>4)*4 + r
#pragma unroll
    for (int r = 0; r < 4; ++r) {
        sred[wave * 544 + frm * 17 + (lane >> 4) * 4 + r]        = acc0[r];
        sred[wave * 544 + (16 + frm) * 17 + (lane >> 4) * 4 + r] = acc1[r];
    }
    __syncthreads();

    // wave-parallel softmax: wave w owns h = 4w + (lane>>4); 16 lanes (tg) per h
    {
        const int h = wave * 4 + (lane >> 4);
        const int tg = lane & 15;
        const int i0 = tg * 17 + h, i1 = (16 + tg) * 17 + h;
        float s0 = (sred[i0] + sred[544 + i0] + sred[1088 + i0] + sred[1632 + i0]) * 0.125f;
        float s1 = (sred[i1] + sred[544 + i1] + sred[1088 + i1] + sred[1632 + i1]) * 0.125f;
        float m = fmaxf(s0, s1);
#pragma unroll
        for (int d = 1; d < 16; d <<= 1) m = fmaxf(m, __shfl_xor(m, d));
        float e0 = __expf(s0 - m), e1 = __expf(s1 - m);
        float den = e0 + e1;
#pragma unroll
        for (int d = 1; d < 16; d <<= 1) den += __shfl_xor(den, d);
        float inv = 1.0f / den;
        p_l[h * 40 + tg]      = f32_to_bf16(e0 * inv);
        p_l[h * 40 + 16 + tg] = f32_to_bf16(e1 * inv);
    }
    __syncthreads();

    // wctx[h][c] = sum_t p[h][t] * ctx[t][c]; wave covers c-range wave*256.
    // Swapped operands: D[m=c-local][n=h] -> lane holds 4 CONSECUTIVE c at h=frm
    // => one uint2 (4x bf16) store per nt instead of 4 scalar stores.
    short8 ap;
#pragma unroll
    for (int j = 0; j < 8; ++j) ap[j] = (short)p_l[frm * 40 + fk + j];

    unsigned short* wbase =
        wctx + (long)bi * 16384 + (long)frm * 1024 + (lane >> 4) * 4;
    __builtin_amdgcn_s_setprio(1);
#pragma unroll 4
    for (int nt = 0; nt < 16; ++nt) {
        int c0 = wave * 256 + nt * 16;
        short8 av;   // A-frag: A[m=c0+frm][k=t=fk+j] = ctx^T column reads
#pragma unroll
        for (int j = 0; j < 8; ++j)
            av[j] = (short)*(const unsigned short*)
                        ((const char*)ctx_t + swzb(fk + j, c0 + frm));
        floatx4 wacc = __builtin_amdgcn_mfma_f32_16x16x32_bf16(
            av, ap, (floatx4)0.0f, 0, 0, 0);
        uint2 st;
        st.x = pack_bf16x2(wacc[0], wacc[1]);
        st.y = pack_bf16x2(wacc[2], wacc[3]);
        *(uint2*)(wbase + c0) = st;
    }
    __builtin_amdgcn_s_setprio(0);
}

// ---------- launch ----------
extern "C" void kernel_launch(void* const* d_in, const int* in_sizes, int n_in,
                              void* d_out, int out_size, void* d_ws, size_t ws_size,
                              hipStream_t stream) {
    const float* x       = (const float*)d_in[0];   // [16,128,1024]
    const float* context = (const float*)d_in[1];   // [16,4096,1024]
    const float* Wq      = (const float*)d_in[2];   // [1024,1024]
    const float* Wkv     = (const float*)d_in[3];   // [1024,2048]
    const float* Wout    = (const float*)d_in[4];   // [1024,1024]
    const float* bout    = (const float*)d_in[5];   // [1024]
    float* out = (float*)d_out;                     // [16,128,1024] fp32

    char* ws = (char*)d_ws;
    unsigned short* WqT   = (unsigned short*)(ws);                       // 2MB
    unsigned short* WkB   = (unsigned short*)(ws + (2ll  << 20));        // 2MB (k-half of Wkv, bf16)
    unsigned short* WvT   = (unsigned short*)(ws + (4ll  << 20));        // 2MB (v-half, transposed)
    unsigned short* WoutT = (unsigned short*)(ws + (6ll  << 20));        // 2MB
    unsigned short* xb    = (unsigned short*)(ws + (8ll  << 20));        // 4MB
    unsigned short* qb    = (unsigned short*)(ws + (12ll << 20));        // 4MB
    unsigned short* aob   = (unsigned short*)(ws + (16ll << 20));        // 4MB
    unsigned short* qtb   = (unsigned short*)(ws + (32ll << 20));        // 64MB [bi][16][1024]
    unsigned short* wctxb = (unsigned short*)(ws + (96ll << 20));        // 64MB [bi][16][1024]

    // prep: weight transposes/casts + x cast
    prep_kernel<<<4608, 256, 0, stream>>>(Wq, Wkv, Wout, x, WqT, WkB, WvT, WoutT, xb);

    // q = x @ Wq                       [2048,1024] bf16   (512 blocks, 2/CU)
    gemm64s_kernel<<<dim3(16, 32, 1), 256, 0, stream>>>(
        xb, 0, 1024, WqT, 0, 1024, qb, 0, 1024, nullptr, 1024, 1);
    // qt[bi][h][c] = q_h[bi] @ Wk_h^T  (K=64 per head, z=h; 4096 blocks)
    gemm64_kernel<<<dim3(16, 16, 16), 256, 0, stream>>>(
        qb, 64, 1024, WkB, 64, 1024, qtb, 1024, 16384, nullptr, 64, 1);
    // fused: s -> softmax -> wctx      [2048][16][1024] bf16
    attn_fused_kernel<<<2048, 256, 0, stream>>>(context, qtb, wctxb);
    // aob[bi][h*64+d] = wctx_h[bi] @ Wv_h   (K=1024, z=h; 512 blocks)
    gemm64s_kernel<<<dim3(1, 32, 16), 256, 0, stream>>>(
        wctxb, 1024, 16384, WvT, (long)64 * 1024, 1024, aob, 64, 1024, nullptr, 1024, 1);
    // out = aob @ Wout + bout          [2048,1024] fp32   (512 blocks, 2/CU)
    gemm64s_kernel<<<dim3(16, 32, 1), 256, 0, stream>>>(
        aob, 0, 1024, WoutT, 0, 1024, out, 0, 1024, bout, 1024, 0);
}

// Round 4
// 446.924 us; speedup vs baseline: 1.0553x; 1.0159x over previous
//
#include <hip/hip_runtime.h>
#include <hip/hip_bf16.h>

typedef __attribute__((ext_vector_type(8))) short short8;
typedef __attribute__((ext_vector_type(4))) float floatx4;

// ---------- helpers ----------
__device__ __forceinline__ unsigned short f32_to_bf16(float f) {
    unsigned int u = __builtin_bit_cast(unsigned int, f);
    u = (u + 0x7FFFu + ((u >> 16) & 1u)) >> 16;   // RNE
    return (unsigned short)u;
}
__device__ __forceinline__ unsigned int pack_bf16x2(float lo, float hi) {
    return (unsigned int)f32_to_bf16(lo) | ((unsigned int)f32_to_bf16(hi) << 16);
}
// async global->LDS, 16B per lane; LDS dest = wave-uniform base + lane*16
__device__ __forceinline__ void async_load16(const unsigned short* g, unsigned short* l) {
    __builtin_amdgcn_global_load_lds(
        (const __attribute__((address_space(1))) void*)g,
        (__attribute__((address_space(3))) void*)l, 16, 0, 0);
}

// ---------- transpose tile: Wt[n][k] = W[k][n_off+n], 32x32 ----------
__device__ __forceinline__ void transpose_tile(
    const float* __restrict__ W, int src_ld, int n_off,
    unsigned short* __restrict__ Wt, int dst_ld, int nb, int kb, int tid) {
    __shared__ float tile[32][33];
    int n0 = nb * 32, k0 = kb * 32;
    int tx = tid & 31, ty = tid >> 5;    // ty 0..7
#pragma unroll
    for (int p = 0; p < 4; ++p) {
        int r = ty + 8 * p;
        tile[r][tx] = W[(long)(k0 + r) * src_ld + n_off + n0 + tx];
    }
    __syncthreads();
#pragma unroll
    for (int p = 0; p < 4; ++p) {
        int r = ty + 8 * p;
        Wt[(long)(n0 + r) * dst_ld + k0 + tx] = f32_to_bf16(tile[tx][r]);
    }
}

__device__ __forceinline__ void cast8(
    const float* __restrict__ src, unsigned short* __restrict__ dst) {
    floatx4 a = *(const floatx4*)src;
    floatx4 b = *(const floatx4*)(src + 4);
    uint4 p;
    p.x = pack_bf16x2(a[0], a[1]); p.y = pack_bf16x2(a[2], a[3]);
    p.z = pack_bf16x2(b[0], b[1]); p.w = pack_bf16x2(b[2], b[3]);
    *(uint4*)dst = p;
}

// nontemporal variant for streamed-once context reads (keep L2/L3 for qt/wctx)
__device__ __forceinline__ void cast8_nt(
    const float* __restrict__ src, unsigned short* __restrict__ dst) {
    floatx4 a = __builtin_nontemporal_load((const floatx4*)src);
    floatx4 b = __builtin_nontemporal_load((const floatx4*)(src + 4));
    uint4 p;
    p.x = pack_bf16x2(a[0], a[1]); p.y = pack_bf16x2(a[2], a[3]);
    p.z = pack_bf16x2(b[0], b[1]); p.w = pack_bf16x2(b[2], b[3]);
    *(uint4*)dst = p;
}

// ---------- fused prep ----------
// blocks: [0,1024) WqT | [1024,2048) WvT | [2048,3072) WoutT |
//         [3072,3584) WkB strided cast | [3584,4608) x cast
__global__ __launch_bounds__(256) void prep_kernel(
    const float* __restrict__ Wq, const float* __restrict__ Wkv,
    const float* __restrict__ Wout, const float* __restrict__ x,
    unsigned short* __restrict__ WqT, unsigned short* __restrict__ WkB,
    unsigned short* __restrict__ WvT, unsigned short* __restrict__ WoutT,
    unsigned short* __restrict__ xb) {
    int id = blockIdx.x, tid = threadIdx.x;
    if (id < 1024) { transpose_tile(Wq,   1024, 0,    WqT,   1024, id & 31, id >> 5, tid); return; }
    id -= 1024;
    if (id < 1024) { transpose_tile(Wkv,  2048, 1024, WvT,   1024, id & 31, id >> 5, tid); return; }
    id -= 1024;
    if (id < 1024) { transpose_tile(Wout, 1024, 0,    WoutT, 1024, id & 31, id >> 5, tid); return; }
    id -= 1024;
    if (id < 512) {   // WkB[c][d] = bf16(Wkv[c][d]), d<1024
        long e = ((long)id * 256 + tid) * 8;
        long row = e >> 10, col = e & 1023;
        cast8(Wkv + row * 2048 + col, WkB + e);
        return;
    }
    id -= 512;
    { long e = ((long)id * 256 + tid) * 8; cast8(x + e, xb + e); }
}

// ---------- GEMM 128x64 tile, K=64 single-stage (qt: per-head small-K) ----------
// BK=64, one stage, one barrier. LDS reads XOR-swizzled (granule g ^= row&7);
// the inverse swizzle is applied to the GLOBAL source address at stage time
// (global_load_lds dest must stay linear: base + lane*16).
__global__ __launch_bounds__(256, 4) void gemm64_kernel(
    const unsigned short* __restrict__ A, long sA, int lda,
    const unsigned short* __restrict__ Bt, long sB, int ldb,
    void* __restrict__ C, long sC, int ldc,
    const float* __restrict__ bias, int K, int out_bf16) {
    __shared__ unsigned short As[128 * 64];   // 16 KB
    __shared__ unsigned short Bs[64 * 64];    // 8 KB

    const int tid = threadIdx.x, wave = tid >> 6, lane = tid & 63;
    const int z = blockIdx.z;
    const int m0 = blockIdx.y * 128, n0 = blockIdx.x * 64;
    const unsigned short* Ab = A  + (long)z * sA + (long)m0 * lda;
    const unsigned short* Bb = Bt + (long)z * sB + (long)n0 * ldb;

    floatx4 acc[2][4];
#pragma unroll
    for (int i = 0; i < 2; ++i)
#pragma unroll
        for (int j = 0; j < 4; ++j) acc[i][j] = (floatx4)0.0f;

    // stage A (128x64 = 4 issue-sets) + B (64x64 = 2 issue-sets)
#pragma unroll
    for (int s = 0; s < 4; ++s) {
        int E = s * 2048 + tid * 8;
        int r = E >> 6, g = ((E >> 3) & 7) ^ (r & 7);
        async_load16(Ab + (long)r * lda + g * 8, &As[s * 2048 + wave * 512]);
    }
#pragma unroll
    for (int s = 0; s < 2; ++s) {
        int E = s * 2048 + tid * 8;
        int r = E >> 6, g = ((E >> 3) & 7) ^ (r & 7);
        async_load16(Bb + (long)r * ldb + g * 8, &Bs[s * 2048 + wave * 512]);
    }
    __syncthreads();   // vmcnt(0) drain + barrier

    const int frm = lane & 15, gq = lane >> 4;
    __builtin_amdgcn_s_setprio(1);
#pragma unroll
    for (int ks = 0; ks < 2; ++ks) {
        const int Ga = ks * 4 + gq;
        short8 a[2];
#pragma unroll
        for (int rt = 0; rt < 2; ++rt) {
            int Ra = wave * 32 + rt * 16 + frm;
            a[rt] = *(const short8*)&As[Ra * 64 + ((Ga ^ (Ra & 7)) << 3)];
        }
#pragma unroll
        for (int ct = 0; ct < 4; ++ct) {
            int Rb = ct * 16 + frm;
            short8 b = *(const short8*)&Bs[Rb * 64 + ((Ga ^ (Rb & 7)) << 3)];
#pragma unroll
            for (int rt = 0; rt < 2; ++rt)
                acc[rt][ct] = __builtin_amdgcn_mfma_f32_16x16x32_bf16(
                    a[rt], b, acc[rt][ct], 0, 0, 0);
        }
    }
    __builtin_amdgcn_s_setprio(0);

    const int orow0 = m0 + wave * 32 + (lane >> 4) * 4;
    const int ocol0 = n0 + (lane & 15);
    if (out_bf16) {
        unsigned short* Cb = (unsigned short*)C + (long)z * sC;
#pragma unroll
        for (int rt = 0; rt < 2; ++rt)
#pragma unroll
            for (int r = 0; r < 4; ++r) {
                long row = orow0 + rt * 16 + r;
#pragma unroll
                for (int ct = 0; ct < 4; ++ct)
                    Cb[row * ldc + ocol0 + ct * 16] = f32_to_bf16(acc[rt][ct][r]);
            }
    } else {
        float* Cf = (float*)C + (long)z * sC;
#pragma unroll
        for (int rt = 0; rt < 2; ++rt)
#pragma unroll
            for (int r = 0; r < 4; ++r) {
                long row = orow0 + rt * 16 + r;
#pragma unroll
                for (int ct = 0; ct < 4; ++ct) {
                    int col = ocol0 + ct * 16;
                    float v = acc[rt][ct][r];
                    if (bias) v += bias[col];
                    Cf[row * ldc + col] = v;
                }
            }
    }
}

// ---------- GEMM 64x64 tile, BK=64, 2-phase prefetch (double-buffered) ----------
// iter t: barrier (drains tile-t loads issued in iter t-1) -> issue tile t+1
// into the other buffer -> ds_read+MFMA tile t. Loads stay in flight across
// the whole compute phase. Same XOR granule swizzle as above.
__global__ __launch_bounds__(256, 4) void gemm64s_kernel(
    const unsigned short* __restrict__ A, long sA, int lda,
    const unsigned short* __restrict__ Bt, long sB, int ldb,
    void* __restrict__ C, long sC, int ldc,
    const float* __restrict__ bias, int K, int out_bf16) {
    __shared__ unsigned short As[2][64 * 64];   // 2 x 8 KB
    __shared__ unsigned short Bs[2][64 * 64];   // 2 x 8 KB

    const int tid = threadIdx.x, wave = tid >> 6, lane = tid & 63;
    const int z = blockIdx.z;
    const int m0 = blockIdx.y * 64, n0 = blockIdx.x * 64;
    const unsigned short* Ab = A  + (long)z * sA + (long)m0 * lda;
    const unsigned short* Bb = Bt + (long)z * sB + (long)n0 * ldb;

    floatx4 acc[4];
#pragma unroll
    for (int j = 0; j < 4; ++j) acc[j] = (floatx4)0.0f;

    const int frm = lane & 15, gq = lane >> 4;
    const int E0 = tid * 8;

    const int nt = K >> 6;
    int cur = 0;
    // prologue: stage tile 0 into buf 0
#pragma unroll
    for (int s = 0; s < 2; ++s) {
        int E = s * 2048 + E0;
        int r = E >> 6, g = ((E >> 3) & 7) ^ (r & 7);
        async_load16(Ab + (long)r * lda + g * 8, &As[0][s * 2048 + wave * 512]);
        async_load16(Bb + (long)r * ldb + g * 8, &Bs[0][s * 2048 + wave * 512]);
    }

    for (int t = 0; t < nt; ++t) {
        __syncthreads();   // per-wave vmcnt(0) + barrier: tile t ready
        if (t + 1 < nt) {
            int kk = (t + 1) << 6;
#pragma unroll
            for (int s = 0; s < 2; ++s) {
                int E = s * 2048 + E0;
                int r = E >> 6, g = ((E >> 3) & 7) ^ (r & 7);
                async_load16(Ab + (long)r * lda + kk + g * 8,
                             &As[cur ^ 1][s * 2048 + wave * 512]);
                async_load16(Bb + (long)r * ldb + kk + g * 8,
                             &Bs[cur ^ 1][s * 2048 + wave * 512]);
            }
        }
        __builtin_amdgcn_s_setprio(1);
#pragma unroll
        for (int ks = 0; ks < 2; ++ks) {
            const int Ga = ks * 4 + gq;
            const int Ra = wave * 16 + frm;
            short8 a = *(const short8*)&As[cur][Ra * 64 + ((Ga ^ (Ra & 7)) << 3)];
#pragma unroll
            for (int ct = 0; ct < 4; ++ct) {
                int Rb = ct * 16 + frm;
                short8 b = *(const short8*)&Bs[cur][Rb * 64 + ((Ga ^ (Rb & 7)) << 3)];
                acc[ct] = __builtin_amdgcn_mfma_f32_16x16x32_bf16(
                    a, b, acc[ct], 0, 0, 0);
            }
        }
        __builtin_amdgcn_s_setprio(0);
        cur ^= 1;
    }

    const int orow0 = m0 + wave * 16 + (lane >> 4) * 4;
    const int ocol0 = n0 + (lane & 15);
    if (out_bf16) {
        unsigned short* Cb = (unsigned short*)C + (long)z * sC;
#pragma unroll
        for (int r = 0; r < 4; ++r) {
            long row = orow0 + r;
#pragma unroll
            for (int ct = 0; ct < 4; ++ct)
                Cb[row * ldc + ocol0 + ct * 16] = f32_to_bf16(acc[ct][r]);
        }
    } else {
        float* Cf = (float*)C + (long)z * sC;
#pragma unroll
        for (int r = 0; r < 4; ++r) {
            long row = orow0 + r;
#pragma unroll
            for (int ct = 0; ct < 4; ++ct) {
                int col = ocol0 + ct * 16;
                float v = acc[ct][r];
                if (bias) v += bias[col];
                Cf[row * ldc + col] = v;
            }
        }
    }
}

// ---------- fused attention: s = qt.ctx^T -> softmax -> wctx = p.ctx ----------
// one block per (b,i); 32 ctx rows j=i+128t loaded once (fp32->bf16 LDS).
// LDS rows XOR-swizzled on t-bits 3..4 (byte bits 5..6): PV column reads go
// from 8-way bank conflict to conflict-free; QK b128 row reads stay <=2-way.
#define CLD 1032   // LDS row stride (elems); rows 16B-aligned
__device__ __forceinline__ int swzb(int t, int c) {   // byte offset into ctx_t
    return t * (2 * CLD) + ((2 * c) ^ (((t >> 3) & 3) << 5));
}
__global__ __launch_bounds__(256, 2) void attn_fused_kernel(
    const float* __restrict__ ctx,          // fp32 [16*4096][1024]
    const unsigned short* __restrict__ qt,  // bf16 [2048][16][1024]
    unsigned short* __restrict__ wctx) {    // bf16 [2048][16][1024]
    __shared__ unsigned short ctx_t[32 * CLD];   // 66 KB (swizzled)
    __shared__ float sred[4 * 544];              // 8.5 KB, stride 17 per t-row
    __shared__ unsigned short p_l[16 * 40];      // p in frag layout [h][t], padded

    const int tid = threadIdx.x, wave = tid >> 6, lane = tid & 63;
    const int bi = blockIdx.x;
    const int b = bi >> 7, i = bi & 127;
    const int frm = lane & 15, fk = (lane >> 4) * 8;

    // preload qt A-frags into registers: lane holds head row frm,
    // k-range wave*256 + it*32 + fk .. +8
    short8 af[8];
    const unsigned short* qbase =
        qt + (long)bi * 16384 + (long)frm * 1024 + wave * 256 + fk;
#pragma unroll
    for (int it = 0; it < 8; ++it) af[it] = *(const short8*)(qbase + it * 32);

    // load ctx rows j=i+128t (fp32 -> bf16, nontemporal, swizzled LDS store)
#pragma unroll
    for (int rr = 0; rr < 16; ++rr) {
        int idx = rr * 2048 + tid * 8;
        int t = idx >> 10, c = idx & 1023;
        cast8_nt(ctx + ((long)b * 4096 + i + t * 128) * 1024 + c,
                 (unsigned short*)((char*)ctx_t + swzb(t, c)));
    }
    __syncthreads();

    // s partials: wave w covers k in [w*256, w*256+256)
    floatx4 acc0 = (floatx4)0.0f, acc1 = (floatx4)0.0f;
    __builtin_amdgcn_s_setprio(1);
#pragma unroll
    for (int it = 0; it < 8; ++it) {
        int kk = wave * 256 + it * 32;
        short8 b0 = *(const short8*)((const char*)ctx_t + swzb(frm, kk + fk));
        short8 b1 = *(const short8*)((const char*)ctx_t + swzb(16 + frm, kk + fk));
        acc0 = __builtin_amdgcn_mfma_f32_16x16x32_bf16(af[it], b0, acc0, 0, 0, 0);
        acc1 = __builtin_amdgcn_mfma_f32_16x16x32_bf16(af[it], b1, acc1, 0, 0, 0);
    }
    __builtin_amdgcn_s_setprio(0);
    // C-layout: t = lane&15 (+16 for acc1), h = (lane>>4)*4 + r
#pragma unroll
    for (int r = 0; r < 4; ++r) {
        sred[wave * 544 + frm * 17 + (lane >> 4) * 4 + r]        = acc0[r];
        sred[wave * 544 + (16 + frm) * 17 + (lane >> 4) * 4 + r] = acc1[r];
    }
    __syncthreads();

    // wave-parallel softmax: wave w owns h = 4w + (lane>>4); 16 lanes (tg) per h
    {
        const int h = wave * 4 + (lane >> 4);
        const int tg = lane & 15;
        const int i0 = tg * 17 + h, i1 = (16 + tg) * 17 + h;
        float s0 = (sred[i0] + sred[544 + i0] + sred[1088 + i0] + sred[1632 + i0]) * 0.125f;
        float s1 = (sred[i1] + sred[544 + i1] + sred[1088 + i1] + sred[1632 + i1]) * 0.125f;
        float m = fmaxf(s0, s1);
#pragma unroll
        for (int d = 1; d < 16; d <<= 1) m = fmaxf(m, __shfl_xor(m, d));
        float e0 = __expf(s0 - m), e1 = __expf(s1 - m);
        float den = e0 + e1;
#pragma unroll
        for (int d = 1; d < 16; d <<= 1) den += __shfl_xor(den, d);
        float inv = 1.0f / den;
        p_l[h * 40 + tg]      = f32_to_bf16(e0 * inv);
        p_l[h * 40 + 16 + tg] = f32_to_bf16(e1 * inv);
    }
    __syncthreads();

    // wctx[h][c] = sum_t p[h][t] * ctx[t][c]; wave covers c-range wave*256.
    // Swapped operands: D[m=c-local][n=h] -> lane holds 4 CONSECUTIVE c at h=frm
    // => one uint2 (4x bf16) store per nt instead of 4 scalar stores.
    short8 ap;
#pragma unroll
    for (int j = 0; j < 8; ++j) ap[j] = (short)p_l[frm * 40 + fk + j];

    unsigned short* wbase =
        wctx + (long)bi * 16384 + (long)frm * 1024 + (lane >> 4) * 4;
    __builtin_amdgcn_s_setprio(1);
#pragma unroll 4
    for (int nt = 0; nt < 16; ++nt) {
        int c0 = wave * 256 + nt * 16;
        short8 av;   // A-frag: A[m=c0+frm][k=t=fk+j] = ctx^T column reads
#pragma unroll
        for (int j = 0; j < 8; ++j)
            av[j] = (short)*(const unsigned short*)
                        ((const char*)ctx_t + swzb(fk + j, c0 + frm));
        floatx4 wacc = __builtin_amdgcn_mfma_f32_16x16x32_bf16(
            av, ap, (floatx4)0.0f, 0, 0, 0);
        uint2 st;
        st.x = pack_bf16x2(wacc[0], wacc[1]);
        st.y = pack_bf16x2(wacc[2], wacc[3]);
        *(uint2*)(wbase + c0) = st;
    }
    __builtin_amdgcn_s_setprio(0);
}

// ---------- launch ----------
extern "C" void kernel_launch(void* const* d_in, const int* in_sizes, int n_in,
                              void* d_out, int out_size, void* d_ws, size_t ws_size,
                              hipStream_t stream) {
    const float* x       = (const float*)d_in[0];   // [16,128,1024]
    const float* context = (const float*)d_in[1];   // [16,4096,1024]
    const float* Wq      = (const float*)d_in[2];   // [1024,1024]
    const float* Wkv     = (const float*)d_in[3];   // [1024,2048]
    const float* Wout    = (const float*)d_in[4];   // [1024,1024]
    const float* bout    = (const float*)d_in[5];   // [1024]
    float* out = (float*)d_out;                     // [16,128,1024] fp32

    char* ws = (char*)d_ws;
    unsigned short* WqT   = (unsigned short*)(ws);                       // 2MB
    unsigned short* WkB   = (unsigned short*)(ws + (2ll  << 20));        // 2MB (k-half of Wkv, bf16)
    unsigned short* WvT   = (unsigned short*)(ws + (4ll  << 20));        // 2MB (v-half, transposed)
    unsigned short* WoutT = (unsigned short*)(ws + (6ll  << 20));        // 2MB
    unsigned short* xb    = (unsigned short*)(ws + (8ll  << 20));        // 4MB
    unsigned short* qb    = (unsigned short*)(ws + (12ll << 20));        // 4MB
    unsigned short* aob   = (unsigned short*)(ws + (16ll << 20));        // 4MB
    unsigned short* qtb   = (unsigned short*)(ws + (32ll << 20));        // 64MB [bi][16][1024]
    unsigned short* wctxb = (unsigned short*)(ws + (96ll << 20));        // 64MB [bi][16][1024]

    // prep: weight transposes/casts + x cast
    prep_kernel<<<4608, 256, 0, stream>>>(Wq, Wkv, Wout, x, WqT, WkB, WvT, WoutT, xb);

    // q = x @ Wq                       [2048,1024] bf16   (512 blocks, 2/CU)
    gemm64s_kernel<<<dim3(16, 32, 1), 256, 0, stream>>>(
        xb, 0, 1024, WqT, 0, 1024, qb, 0, 1024, nullptr, 1024, 1);
    // qt[bi][h][c] = q_h[bi] @ Wk_h^T  (K=64 per head, z=h; 4096 blocks)
    gemm64_kernel<<<dim3(16, 16, 16), 256, 0, stream>>>(
        qb, 64, 1024, WkB, 64, 1024, qtb, 1024, 16384, nullptr, 64, 1);
    // fused: s -> softmax -> wctx      [2048][16][1024] bf16
    attn_fused_kernel<<<2048, 256, 0, stream>>>(context, qtb, wctxb);
    // aob[bi][h*64+d] = wctx_h[bi] @ Wv_h   (K=1024, z=h; 512 blocks)
    gemm64s_kernel<<<dim3(1, 32, 16), 256, 0, stream>>>(
        wctxb, 1024, 16384, WvT, (long)64 * 1024, 1024, aob, 64, 1024, nullptr, 1024, 1);
    // out = aob @ Wout + bout          [2048,1024] fp32   (512 blocks, 2/CU)
    gemm64s_kernel<<<dim3(16, 32, 1), 256, 0, stream>>>(
        aob, 0, 1024, WoutT, 0, 1024, out, 0, 1024, bout, 1024, 0);
}